// Round 4
// baseline (60.512 us; speedup 1.0000x reference)
//
#include <hip/hip_runtime.h>
#include <hip/hip_bf16.h>
#include <stdint.h>

// Problem: out[N,OUT] = x[N,IN] @ weight[OUT,IN]^T + bias[OUT]
// N=4096, IN(K)=2048, OUT=2048, all fp32 in/out.
#define NROWS 4096
#define KDIM  2048
#define ODIM  2048
#define BM    256
#define BN    128
#define BK    64
#define NT    (KDIM / BK)   // 32 K-tiles

typedef __bf16 bf16x8 __attribute__((ext_vector_type(8)));
typedef float  f32x4  __attribute__((ext_vector_type(4)));
typedef unsigned short u16;
typedef unsigned int   u32;

__device__ __forceinline__ u16 f32_to_bf16_rne(float f) {
  u32 u = __builtin_bit_cast(u32, f);
  u += 0x7FFFu + ((u >> 16) & 1u);
  return (u16)(u >> 16);
}

// fused fp32 -> bf16 conversion for BOTH x and w (grid-stride), HBM-roofline
__global__ void cvt_both_f32_to_bf16(const float* __restrict__ x,
                                     const float* __restrict__ w,
                                     u16* __restrict__ xb, u16* __restrict__ wb,
                                     int n4x, int n4w) {
  int i = blockIdx.x * blockDim.x + threadIdx.x;
  const int stride = gridDim.x * blockDim.x;
  const int total = n4x + n4w;
  for (; i < total; i += stride) {
    const float4* in;
    ushort4* out;
    int j;
    if (i < n4x) { in = (const float4*)x; out = (ushort4*)xb; j = i; }
    else         { in = (const float4*)w; out = (ushort4*)wb; j = i - n4x; }
    float4 v = in[j];
    ushort4 o;
    o.x = f32_to_bf16_rne(v.x);
    o.y = f32_to_bf16_rne(v.y);
    o.z = f32_to_bf16_rne(v.z);
    o.w = f32_to_bf16_rne(v.w);
    out[j] = o;
  }
}

// async global->LDS, 16B/lane; LDS dest is wave-uniform base (+lane*16 in HW)
__device__ __forceinline__ void async16(const u16* g, const u16* l) {
  __builtin_amdgcn_global_load_lds((const __attribute__((address_space(1))) u32*)g,
                                   (__attribute__((address_space(3))) u32*)l,
                                   16, 0, 0);
}

// BM=256 x BN=128 tile, BK=64, 512 threads = 8 waves (4Mx2N), per-wave 64x64
// (4x4 frags of 16x16x32). Double-buffered LDS (96 KB), early-issue staging,
// ONE barrier+drain per K-tile, compile-time buffer indices (2x unroll).
// LDS swizzle: LDS[row][cg] = global[row][cg ^ (row&7)] (cg = 8-u16 group),
// achieved by inverse-swizzled GLOBAL source col with linear gload_lds dest;
// reads XOR the same term -> uniform 8 lanes/16B-slot (b128 floor).
__global__ void __launch_bounds__(512, 2)
gemm_bt_bf16(const u16* __restrict__ A, const u16* __restrict__ B,
             const float* __restrict__ bias, float* __restrict__ C) {
  __shared__ __align__(16) u16 As[2 * BM * BK];  // 64 KB
  __shared__ __align__(16) u16 Bs[2 * BN * BK];  // 32 KB

  const int t    = threadIdx.x;
  const int lane = t & 63;
  const int wave = t >> 6;      // 0..7
  const int wrow = wave >> 1;   // 0..3 (M)
  const int wcol = wave & 1;    // 0..1 (N)
  const int fr   = lane & 15;
  const int fq   = lane >> 4;

  // T1 XCD swizzle: 256 blocks, 256%8==0 -> bijective simple form.
  const int bid  = blockIdx.x;
  const int swz  = (bid & 7) * 32 + (bid >> 3);
  const int brow = (swz >> 4) * BM;   // 16 row-panels
  const int bcol = (swz & 15) * BN;   // 16 col-panels

  // ---- staging: srow 0..63 per issue; inverse-swizzled global col ----
  const int srow = t >> 3;                          // 0..63
  const int scol = ((t & 7) ^ (srow & 7)) * 8;      // u16 units
  const u16* pA = A + (size_t)(brow + srow) * KDIM + scol;
  const u16* pB = B + (size_t)(bcol + srow) * KDIM + scol;

  f32x4 acc[4][4] = {};

  const int xr   = fr & 7;            // read-side XOR (row&7 == fr&7)
  const int arow = wrow * 64 + fr;    // + m*16
  const int brf  = wcol * 64 + fr;    // + n*16

#define STAGE(buf)                                                       \
  do {                                                                   \
    u16* la = As + (buf) * (BM * BK) + wave * 512;                       \
    u16* lb = Bs + (buf) * (BN * BK) + wave * 512;                       \
    async16(pA,                       la);                               \
    async16(pA + (size_t) 64 * KDIM,  la + 4096);                        \
    async16(pA + (size_t)128 * KDIM,  la + 8192);                        \
    async16(pA + (size_t)192 * KDIM,  la + 12288);                       \
    async16(pB,                       lb);                               \
    async16(pB + (size_t) 64 * KDIM,  lb + 4096);                        \
    pA += BK; pB += BK;                                                  \
  } while (0)

#define COMPUTE(buf)                                                     \
  do {                                                                   \
    const u16* ab = As + (buf) * (BM * BK);                              \
    const u16* bb = Bs + (buf) * (BN * BK);                              \
    bf16x8 af[2][4], bf[2][4];                                           \
    _Pragma("unroll")                                                    \
    for (int kk = 0; kk < 2; ++kk) {                                     \
      const int cg = ((kk * 4 + fq) ^ xr) * 8;                           \
      _Pragma("unroll")                                                  \
      for (int m = 0; m < 4; ++m)                                        \
        af[kk][m] = *reinterpret_cast<const bf16x8*>(                    \
            ab + (arow + m * 16) * BK + cg);                             \
      _Pragma("unroll")                                                  \
      for (int n = 0; n < 4; ++n)                                        \
        bf[kk][n] = *reinterpret_cast<const bf16x8*>(                    \
            bb + (brf + n * 16) * BK + cg);                              \
    }                                                                    \
    __builtin_amdgcn_s_setprio(1);                                       \
    _Pragma("unroll")                                                    \
    for (int kk = 0; kk < 2; ++kk)                                       \
      _Pragma("unroll")                                                  \
      for (int m = 0; m < 4; ++m)                                        \
        _Pragma("unroll")                                                \
        for (int n = 0; n < 4; ++n)                                      \
          acc[m][n] = __builtin_amdgcn_mfma_f32_16x16x32_bf16(           \
              af[kk][m], bf[kk][n], acc[m][n], 0, 0, 0);                 \
    __builtin_amdgcn_s_setprio(0);                                       \
  } while (0)

  // prologue: stage tile 0 into buffer 0
  STAGE(0);
  __syncthreads();                     // drain vmcnt(0): buf0 ready

#pragma unroll 1
  for (int it = 0; it < NT / 2 - 1; ++it) {   // 15 iters = tiles 0..29
    STAGE(1);                          // issue EARLY: hidden under COMPUTE(0)
    COMPUTE(0);
    __syncthreads();                   // drain (loads are ~1 compute-phase old)
    STAGE(0);
    COMPUTE(1);
    __syncthreads();
  }
  STAGE(1);
  COMPUTE(0);
  __syncthreads();
  COMPUTE(1);                          // last tile, no prefetch

#undef STAGE
#undef COMPUTE

  // ---- epilogue: C/D layout col=lane&15, row=(lane>>4)*4+reg ----
  float bv[4];
#pragma unroll
  for (int n = 0; n < 4; ++n)
    bv[n] = bias[bcol + wcol * 64 + n * 16 + fr];
#pragma unroll
  for (int m = 0; m < 4; ++m) {
    const int row0 = brow + wrow * 64 + m * 16 + fq * 4;
#pragma unroll
    for (int n = 0; n < 4; ++n) {
      const int col = bcol + wcol * 64 + n * 16 + fr;
      float* o = C + (size_t)row0 * ODIM + col;
#pragma unroll
      for (int j = 0; j < 4; ++j)
        o[(size_t)j * ODIM] = acc[m][n][j] + bv[n];
    }
  }
}

// correctness-only fallback if ws is too small (fp32, 16x16 LDS tiles)
__global__ void fallback_gemm(const float* __restrict__ x, const float* __restrict__ w,
                              const float* __restrict__ bias, float* __restrict__ out) {
  __shared__ float xs[16][17];
  __shared__ float wsm[16][17];
  const int tx = threadIdx.x & 15, ty = threadIdx.x >> 4;
  const int row = blockIdx.y * 16 + ty;
  const int colb = blockIdx.x * 16;
  float acc = 0.f;
  for (int k0 = 0; k0 < KDIM; k0 += 16) {
    xs[ty][tx]  = x[(size_t)row * KDIM + k0 + tx];
    wsm[ty][tx] = w[(size_t)(colb + ty) * KDIM + k0 + tx];
    __syncthreads();
#pragma unroll
    for (int kk = 0; kk < 16; ++kk)
      acc += xs[ty][kk] * wsm[tx][kk];
    __syncthreads();
  }
  out[(size_t)row * ODIM + colb + tx] = acc + bias[colb + tx];
}

extern "C" void kernel_launch(void* const* d_in, const int* in_sizes, int n_in,
                              void* d_out, int out_size, void* d_ws, size_t ws_size,
                              hipStream_t stream) {
  const float* x    = (const float*)d_in[0];
  const float* w    = (const float*)d_in[1];
  const float* bias = (const float*)d_in[2];
  float* out = (float*)d_out;

  const size_t needA = (size_t)NROWS * KDIM * sizeof(u16); // 16 MiB
  const size_t needB = (size_t)ODIM  * KDIM * sizeof(u16); //  8 MiB
  if (ws_size < needA + needB) {
    dim3 grid(ODIM / 16, NROWS / 16);
    fallback_gemm<<<grid, 256, 0, stream>>>(x, w, bias, out);
    return;
  }

  u16* xb = (u16*)d_ws;
  u16* wb = xb + (size_t)NROWS * KDIM;

  const int n4x = NROWS * KDIM / 4;  // 2M float4
  const int n4w = ODIM * KDIM / 4;   // 1M float4
  cvt_both_f32_to_bf16<<<2048, 256, 0, stream>>>(x, w, xb, wb, n4x, n4w);

  const int nblocks = (NROWS / BM) * (ODIM / BN);  // 16*16 = 256
  gemm_bt_bf16<<<nblocks, 512, 0, stream>>>(xb, wb, bias, out);
}

// Round 5
// 56.492 us; speedup vs baseline: 1.0712x; 1.0712x over previous
//
#include <hip/hip_runtime.h>
#include <hip/hip_bf16.h>
#include <stdint.h>

// Problem: out[N,OUT] = x[N,IN] @ weight[OUT,IN]^T + bias[OUT]
// N=4096, IN(K)=2048, OUT=2048, all fp32 in/out.
#define NROWS 4096
#define KDIM  2048
#define ODIM  2048
#define BM    256
#define BN    128
#define BK    64
#define NT    (KDIM / BK)   // 32 K-tiles

typedef __bf16 bf16x8 __attribute__((ext_vector_type(8)));
typedef float  f32x4  __attribute__((ext_vector_type(4)));
typedef unsigned short u16;
typedef unsigned int   u32;

__device__ __forceinline__ u16 f32_to_bf16_rne(float f) {
  u32 u = __builtin_bit_cast(u32, f);
  u += 0x7FFFu + ((u >> 16) & 1u);
  return (u16)(u >> 16);
}

// fused fp32 -> bf16 conversion for BOTH x and w (grid-stride)
__global__ void cvt_both_f32_to_bf16(const float* __restrict__ x,
                                     const float* __restrict__ w,
                                     u16* __restrict__ xb, u16* __restrict__ wb,
                                     int n4x, int n4w) {
  int i = blockIdx.x * blockDim.x + threadIdx.x;
  const int stride = gridDim.x * blockDim.x;
  const int total = n4x + n4w;
  for (; i < total; i += stride) {
    const float4* in;
    ushort4* out;
    int j;
    if (i < n4x) { in = (const float4*)x; out = (ushort4*)xb; j = i; }
    else         { in = (const float4*)w; out = (ushort4*)wb; j = i - n4x; }
    float4 v = in[j];
    ushort4 o;
    o.x = f32_to_bf16_rne(v.x);
    o.y = f32_to_bf16_rne(v.y);
    o.z = f32_to_bf16_rne(v.z);
    o.w = f32_to_bf16_rne(v.w);
    out[j] = o;
  }
}

// async global->LDS, 16B/lane; LDS dest is wave-uniform base (+lane*16 in HW)
__device__ __forceinline__ void async16(const u16* g, const u16* l) {
  __builtin_amdgcn_global_load_lds((const __attribute__((address_space(1))) u32*)g,
                                   (__attribute__((address_space(3))) u32*)l,
                                   16, 0, 0);
}

// BM=256 x BN=128, BK=64, 512 threads = 8 waves (4Mx2N), per-wave 64x64.
// T4 counted-vmcnt pipeline: depth-2 prefetch, raw s_barrier, per-tile
// protocol { vmcnt(6); barrier; COMPUTE; barrier; STAGE(+2) } — the vmcnt
// never drains to 0 in the main loop. Wait-BEFORE-barrier makes each wave's
// "my 6 tile-t loads landed" cover all waves' tile-t loads after the barrier.
// LDS swizzle: LDS[row][cg] = global[row][cg ^ (row&7)] (cg = 8-u16 group),
// via inverse-swizzled GLOBAL source col + linear gload_lds dest (rule 21).
__global__ void __launch_bounds__(512, 2)
gemm_bt_bf16(const u16* __restrict__ A, const u16* __restrict__ B,
             const float* __restrict__ bias, float* __restrict__ C) {
  __shared__ __align__(16) u16 As[2 * BM * BK];  // 64 KB
  __shared__ __align__(16) u16 Bs[2 * BN * BK];  // 32 KB

  const int t    = threadIdx.x;
  const int lane = t & 63;
  const int wave = t >> 6;      // 0..7
  const int wrow = wave >> 1;   // 0..3 (M)
  const int wcol = wave & 1;    // 0..1 (N)
  const int fr   = lane & 15;
  const int fq   = lane >> 4;

  // T1 XCD swizzle: 256 blocks, 256%8==0 -> bijective simple form.
  const int bid  = blockIdx.x;
  const int swz  = (bid & 7) * 32 + (bid >> 3);
  const int brow = (swz >> 4) * BM;   // 16 row-panels
  const int bcol = (swz & 15) * BN;   // 16 col-panels

  // staging: srow 0..63 per issue; inverse-swizzled global col
  const int srow = t >> 3;                          // 0..63
  const int scol = ((t & 7) ^ (srow & 7)) * 8;      // u16 units
  const u16* pA = A + (size_t)(brow + srow) * KDIM + scol;
  const u16* pB = B + (size_t)(bcol + srow) * KDIM + scol;

  f32x4 acc[4][4] = {};

  const int xr   = fr & 7;            // read-side XOR (row&7 == fr&7)
  const int arow = wrow * 64 + fr;    // + m*16
  const int brf  = wcol * 64 + fr;    // + n*16

#define STAGE(buf)                                                       \
  do {                                                                   \
    u16* la = As + (buf) * (BM * BK) + wave * 512;                       \
    u16* lb = Bs + (buf) * (BN * BK) + wave * 512;                       \
    async16(pA,                       la);                               \
    async16(pA + (size_t) 64 * KDIM,  la + 4096);                        \
    async16(pA + (size_t)128 * KDIM,  la + 8192);                        \
    async16(pA + (size_t)192 * KDIM,  la + 12288);                       \
    async16(pB,                       lb);                               \
    async16(pB + (size_t) 64 * KDIM,  lb + 4096);                        \
    pA += BK; pB += BK;                                                  \
  } while (0)

#define COMPUTE(buf)                                                     \
  do {                                                                   \
    const u16* ab = As + (buf) * (BM * BK);                              \
    const u16* bb = Bs + (buf) * (BN * BK);                              \
    bf16x8 af[2][4], bf[2][4];                                           \
    _Pragma("unroll")                                                    \
    for (int kk = 0; kk < 2; ++kk) {                                     \
      const int cg = ((kk * 4 + fq) ^ xr) * 8;                           \
      _Pragma("unroll")                                                  \
      for (int m = 0; m < 4; ++m)                                        \
        af[kk][m] = *reinterpret_cast<const bf16x8*>(                    \
            ab + (arow + m * 16) * BK + cg);                             \
      _Pragma("unroll")                                                  \
      for (int n = 0; n < 4; ++n)                                        \
        bf[kk][n] = *reinterpret_cast<const bf16x8*>(                    \
            bb + (brf + n * 16) * BK + cg);                              \
    }                                                                    \
    __builtin_amdgcn_s_setprio(1);                                       \
    _Pragma("unroll")                                                    \
    for (int kk = 0; kk < 2; ++kk)                                       \
      _Pragma("unroll")                                                  \
      for (int m = 0; m < 4; ++m)                                        \
        _Pragma("unroll")                                                \
        for (int n = 0; n < 4; ++n)                                      \
          acc[m][n] = __builtin_amdgcn_mfma_f32_16x16x32_bf16(           \
              af[kk][m], bf[kk][n], acc[m][n], 0, 0, 0);                 \
    __builtin_amdgcn_s_setprio(0);                                       \
  } while (0)

#define WAIT6 do { asm volatile("s_waitcnt vmcnt(6)" ::: "memory"); } while (0)
#define WAIT0 do { asm volatile("s_waitcnt vmcnt(0)" ::: "memory"); } while (0)
#define BAR   do { __builtin_amdgcn_s_barrier();                         \
                   __builtin_amdgcn_sched_barrier(0); } while (0)

  // prologue: depth-2 prefetch (tiles 0,1) -> 12 loads in flight per wave
  STAGE(0);
  STAGE(1);

#pragma unroll 1
  for (int it = 0; it < NT / 2 - 1; ++it) {   // tiles 2it, 2it+1; stages +2,+3
    WAIT6; BAR;            // tile 2it landed (everyone, after barrier)
    COMPUTE(0);
    BAR;                   // all waves done reading buf0
    STAGE(0);              // tile 2it+2 -> buf0; back to 12 in flight
    WAIT6; BAR;            // tile 2it+1 landed
    COMPUTE(1);
    BAR;
    STAGE(1);              // tile 2it+3 -> buf1
  }
  // tiles NT-2, NT-1 (no more staging)
  WAIT6; BAR;
  COMPUTE(0);
  BAR;
  WAIT0; BAR;
  COMPUTE(1);

#undef STAGE
#undef COMPUTE
#undef WAIT6
#undef WAIT0
#undef BAR

  // ---- epilogue: C/D layout col=lane&15, row=(lane>>4)*4+reg ----
  float bv[4];
#pragma unroll
  for (int n = 0; n < 4; ++n)
    bv[n] = bias[bcol + wcol * 64 + n * 16 + fr];
#pragma unroll
  for (int m = 0; m < 4; ++m) {
    const int row0 = brow + wrow * 64 + m * 16 + fq * 4;
#pragma unroll
    for (int n = 0; n < 4; ++n) {
      const int col = bcol + wcol * 64 + n * 16 + fr;
      float* o = C + (size_t)row0 * ODIM + col;
#pragma unroll
      for (int j = 0; j < 4; ++j)
        o[(size_t)j * ODIM] = acc[m][n][j] + bv[n];
    }
  }
}

// correctness-only fallback if ws is too small (fp32, 16x16 LDS tiles)
__global__ void fallback_gemm(const float* __restrict__ x, const float* __restrict__ w,
                              const float* __restrict__ bias, float* __restrict__ out) {
  __shared__ float xs[16][17];
  __shared__ float wsm[16][17];
  const int tx = threadIdx.x & 15, ty = threadIdx.x >> 4;
  const int row = blockIdx.y * 16 + ty;
  const int colb = blockIdx.x * 16;
  float acc = 0.f;
  for (int k0 = 0; k0 < KDIM; k0 += 16) {
    xs[ty][tx]  = x[(size_t)row * KDIM + k0 + tx];
    wsm[ty][tx] = w[(size_t)(colb + ty) * KDIM + k0 + tx];
    __syncthreads();
#pragma unroll
    for (int kk = 0; kk < 16; ++kk)
      acc += xs[ty][kk] * wsm[tx][kk];
    __syncthreads();
  }
  out[(size_t)row * ODIM + colb + tx] = acc + bias[colb + tx];
}

extern "C" void kernel_launch(void* const* d_in, const int* in_sizes, int n_in,
                              void* d_out, int out_size, void* d_ws, size_t ws_size,
                              hipStream_t stream) {
  const float* x    = (const float*)d_in[0];
  const float* w    = (const float*)d_in[1];
  const float* bias = (const float*)d_in[2];
  float* out = (float*)d_out;

  const size_t needA = (size_t)NROWS * KDIM * sizeof(u16); // 16 MiB
  const size_t needB = (size_t)ODIM  * KDIM * sizeof(u16); //  8 MiB
  if (ws_size < needA + needB) {
    dim3 grid(ODIM / 16, NROWS / 16);
    fallback_gemm<<<grid, 256, 0, stream>>>(x, w, bias, out);
    return;
  }

  u16* xb = (u16*)d_ws;
  u16* wb = xb + (size_t)NROWS * KDIM;

  const int n4x = NROWS * KDIM / 4;  // 2M float4
  const int n4w = ODIM * KDIM / 4;   // 1M float4
  cvt_both_f32_to_bf16<<<2048, 256, 0, stream>>>(x, w, xb, wb, n4x, n4w);

  const int nblocks = (NROWS / BM) * (ODIM / BN);  // 16*16 = 256
  gemm_bt_bf16<<<nblocks, 512, 0, stream>>>(xb, wb, bias, out);
}

// Round 6
// 53.224 us; speedup vs baseline: 1.1369x; 1.0614x over previous
//
#include <hip/hip_runtime.h>
#include <hip/hip_bf16.h>
#include <stdint.h>

// Problem: out[N,OUT] = x[N,IN] @ weight[OUT,IN]^T + bias[OUT]
// N=4096, IN(K)=2048, OUT=2048, all fp32 in/out.
#define NROWS 4096
#define KDIM  2048
#define ODIM  2048
#define BM    256
#define BN    128
#define BK    64
#define NT    (KDIM / BK)   // 32 K-tiles

typedef __bf16 bf16x8 __attribute__((ext_vector_type(8)));
typedef float  f32x4  __attribute__((ext_vector_type(4)));
typedef unsigned short u16;
typedef unsigned int   u32;

__device__ __forceinline__ u16 f32_to_bf16_rne(float f) {
  u32 u = __builtin_bit_cast(u32, f);
  u += 0x7FFFu + ((u >> 16) & 1u);
  return (u16)(u >> 16);
}

// fused fp32 -> bf16 conversion for BOTH x and w (grid-stride); HBM-roofline
__global__ void cvt_both_f32_to_bf16(const float* __restrict__ x,
                                     const float* __restrict__ w,
                                     u16* __restrict__ xb, u16* __restrict__ wb,
                                     int n4x, int n4w) {
  int i = blockIdx.x * blockDim.x + threadIdx.x;
  const int stride = gridDim.x * blockDim.x;
  const int total = n4x + n4w;
  for (; i < total; i += stride) {
    const float4* in;
    ushort4* out;
    int j;
    if (i < n4x) { in = (const float4*)x; out = (ushort4*)xb; j = i; }
    else         { in = (const float4*)w; out = (ushort4*)wb; j = i - n4x; }
    float4 v = in[j];
    ushort4 o;
    o.x = f32_to_bf16_rne(v.x);
    o.y = f32_to_bf16_rne(v.y);
    o.z = f32_to_bf16_rne(v.z);
    o.w = f32_to_bf16_rne(v.w);
    out[j] = o;
  }
}

// async global->LDS, 16B/lane; LDS dest is wave-uniform base (+lane*16 in HW)
__device__ __forceinline__ void async16(const u16* g, const u16* l) {
  __builtin_amdgcn_global_load_lds((const __attribute__((address_space(1))) u32*)g,
                                   (__attribute__((address_space(3))) u32*)l,
                                   16, 0, 0);
}

// BM=256 x BN=128, BK=64, 512 threads = 8 waves (4Mx2N), per-wave 64x64.
// TRIPLE-buffered LDS (144 KB), depth-2 prefetch: during tile t's compute,
// stage tile t+2 into buf[(t+2)%3] (free since tile t-1's barrier). ONE
// vmcnt(6)+s_barrier per K-tile; no intra-tile barriers -> compiler overlaps
// ds_read/MFMA across kk-phases; setprio(1) wraps each MFMA cluster (T5).
// Race-freedom: reads of buf[t%3] gated by per-wave vmcnt(6) (tile t's 6
// loads are older than the newest 6 = tile t+1's) + barrier; stage writes to
// buf[(t+2)%3] are issued after the tile-t barrier, and all tile t-1 ds_reads
// of that buffer completed before it (their MFMAs consumed them pre-barrier).
// LDS swizzle (T2): LDS[row][cg] = global[row][cg ^ (row&7)] (cg=8-u16 group)
// via inverse-swizzled GLOBAL src col + linear gload_lds dest; reads XOR same.
__global__ void __launch_bounds__(512, 2)
gemm_bt_bf16(const u16* __restrict__ A, const u16* __restrict__ B,
             const float* __restrict__ bias, float* __restrict__ C) {
  __shared__ __align__(16) u16 As[3 * BM * BK];  // 96 KB
  __shared__ __align__(16) u16 Bs[3 * BN * BK];  // 48 KB

  const int t    = threadIdx.x;
  const int lane = t & 63;
  const int wave = t >> 6;      // 0..7
  const int wrow = wave >> 1;   // 0..3 (M)
  const int wcol = wave & 1;    // 0..1 (N)
  const int fr   = lane & 15;
  const int fq   = lane >> 4;

  // T1 XCD swizzle: 256 blocks, 256%8==0 -> bijective simple form.
  const int bid  = blockIdx.x;
  const int swz  = (bid & 7) * 32 + (bid >> 3);
  const int brow = (swz >> 4) * BM;   // 16 row-panels
  const int bcol = (swz & 15) * BN;   // 16 col-panels

  // staging: srow 0..63 per issue; inverse-swizzled global col
  const int srow = t >> 3;                          // 0..63
  const int scol = ((t & 7) ^ (srow & 7)) * 8;      // u16 units
  const u16* pA = A + (size_t)(brow + srow) * KDIM + scol;
  const u16* pB = B + (size_t)(bcol + srow) * KDIM + scol;

  f32x4 acc[4][4] = {};

  const int xr   = fr & 7;            // read-side XOR (row&7 == fr&7)
  const int arow = wrow * 64 + fr;    // + m*16
  const int brf  = wcol * 64 + fr;    // + n*16

  // ---- one K-tile: wait+barrier, 2 kk-phases, staging interleaved ----
  // bi: compile-time buffer index of the tile being computed.
  // DOSTG: stage tile (t+2) into buf (bi+2)%3 at column offset KOFF (elems).
#define TILE(bi, DOSTG, KOFF, VMN)                                       \
  do {                                                                   \
    asm volatile("s_waitcnt vmcnt(" #VMN ")" ::: "memory");              \
    __builtin_amdgcn_s_barrier();                                        \
    __builtin_amdgcn_sched_barrier(0);                                   \
    const u16* ab = As + (bi) * (BM * BK);                               \
    const u16* bb = Bs + (bi) * (BN * BK);                               \
    bf16x8 af[2][4], bf[2][4];                                           \
    { const int cg = ((0 * 4 + fq) ^ xr) * 8;                            \
      _Pragma("unroll")                                                  \
      for (int m = 0; m < 4; ++m)                                        \
        af[0][m] = *reinterpret_cast<const bf16x8*>(                     \
            ab + (arow + m * 16) * BK + cg);                             \
      _Pragma("unroll")                                                  \
      for (int n = 0; n < 4; ++n)                                        \
        bf[0][n] = *reinterpret_cast<const bf16x8*>(                     \
            bb + (brf + n * 16) * BK + cg); }                            \
    if (DOSTG) {                                                         \
      u16* la = As + (((bi) + 2) % 3) * (BM * BK) + wave * 512;          \
      async16(pA + (KOFF),                       la);                    \
      async16(pA + (size_t) 64 * KDIM + (KOFF),  la + 4096);             \
      async16(pA + (size_t)128 * KDIM + (KOFF),  la + 8192);             \
    }                                                                    \
    __builtin_amdgcn_s_setprio(1);                                       \
    _Pragma("unroll")                                                    \
    for (int m = 0; m < 4; ++m)                                          \
      _Pragma("unroll")                                                  \
      for (int n = 0; n < 4; ++n)                                        \
        acc[m][n] = __builtin_amdgcn_mfma_f32_16x16x32_bf16(             \
            af[0][m], bf[0][n], acc[m][n], 0, 0, 0);                     \
    __builtin_amdgcn_s_setprio(0);                                       \
    { const int cg = ((1 * 4 + fq) ^ xr) * 8;                            \
      _Pragma("unroll")                                                  \
      for (int m = 0; m < 4; ++m)                                        \
        af[1][m] = *reinterpret_cast<const bf16x8*>(                     \
            ab + (arow + m * 16) * BK + cg);                             \
      _Pragma("unroll")                                                  \
      for (int n = 0; n < 4; ++n)                                        \
        bf[1][n] = *reinterpret_cast<const bf16x8*>(                     \
            bb + (brf + n * 16) * BK + cg); }                            \
    if (DOSTG) {                                                         \
      u16* la = As + (((bi) + 2) % 3) * (BM * BK) + wave * 512;          \
      u16* lb = Bs + (((bi) + 2) % 3) * (BN * BK) + wave * 512;          \
      async16(pA + (size_t)192 * KDIM + (KOFF),  la + 12288);            \
      async16(pB + (KOFF),                       lb);                    \
      async16(pB + (size_t) 64 * KDIM + (KOFF),  lb + 4096);             \
    }                                                                    \
    __builtin_amdgcn_s_setprio(1);                                       \
    _Pragma("unroll")                                                    \
    for (int m = 0; m < 4; ++m)                                          \
      _Pragma("unroll")                                                  \
      for (int n = 0; n < 4; ++n)                                        \
        acc[m][n] = __builtin_amdgcn_mfma_f32_16x16x32_bf16(             \
            af[1][m], bf[1][n], acc[m][n], 0, 0, 0);                     \
    __builtin_amdgcn_s_setprio(0);                                       \
  } while (0)

  // prologue: stage tile 0 -> buf0 (koff 0), tile 1 -> buf1 (koff BK)
  {
    u16* la = As + wave * 512;
    u16* lb = Bs + wave * 512;
    async16(pA,                      la);
    async16(pA + (size_t) 64 * KDIM, la + 4096);
    async16(pA + (size_t)128 * KDIM, la + 8192);
    async16(pA + (size_t)192 * KDIM, la + 12288);
    async16(pB,                      lb);
    async16(pB + (size_t) 64 * KDIM, lb + 4096);
    la = As + (BM * BK) + wave * 512;
    lb = Bs + (BN * BK) + wave * 512;
    async16(pA + BK,                      la);
    async16(pA + (size_t) 64 * KDIM + BK, la + 4096);
    async16(pA + (size_t)128 * KDIM + BK, la + 8192);
    async16(pA + (size_t)192 * KDIM + BK, la + 12288);
    async16(pB + BK,                      lb);
    async16(pB + (size_t) 64 * KDIM + BK, lb + 4096);
  }

  // main loop: 10 iters x 3 tiles = tiles 0..29; stages tiles 2..31
#pragma unroll 1
  for (int i = 0; i < NT / 3; ++i) {     // NT/3 = 10 (tiles 0..29)
    TILE(0, true, 2 * BK, 6);            // compute 3i+0, stage 3i+2 -> buf2
    TILE(1, true, 3 * BK, 6);            // compute 3i+1, stage 3i+3 -> buf0
    TILE(2, true, 4 * BK, 6);            // compute 3i+2, stage 3i+4 -> buf1
    pA += 3 * BK;
    pB += 3 * BK;
  }
  // epilogue: tiles 30 (buf0), 31 (buf1) — no staging
  TILE(0, false, 0, 6);
  TILE(1, false, 0, 0);

#undef TILE

  // ---- epilogue: C/D layout col=lane&15, row=(lane>>4)*4+reg ----
  float bv[4];
#pragma unroll
  for (int n = 0; n < 4; ++n)
    bv[n] = bias[bcol + wcol * 64 + n * 16 + fr];
#pragma unroll
  for (int m = 0; m < 4; ++m) {
    const int row0 = brow + wrow * 64 + m * 16 + fq * 4;
#pragma unroll
    for (int n = 0; n < 4; ++n) {
      const int col = bcol + wcol * 64 + n * 16 + fr;
      float* o = C + (size_t)row0 * ODIM + col;
#pragma unroll
      for (int j = 0; j < 4; ++j)
        o[(size_t)j * ODIM] = acc[m][n][j] + bv[n];
    }
  }
}

// correctness-only fallback if ws is too small (fp32, 16x16 LDS tiles)
__global__ void fallback_gemm(const float* __restrict__ x, const float* __restrict__ w,
                              const float* __restrict__ bias, float* __restrict__ out) {
  __shared__ float xs[16][17];
  __shared__ float wsm[16][17];
  const int tx = threadIdx.x & 15, ty = threadIdx.x >> 4;
  const int row = blockIdx.y * 16 + ty;
  const int colb = blockIdx.x * 16;
  float acc = 0.f;
  for (int k0 = 0; k0 < KDIM; k0 += 16) {
    xs[ty][tx]  = x[(size_t)row * KDIM + k0 + tx];
    wsm[ty][tx] = w[(size_t)(colb + ty) * KDIM + k0 + tx];
    __syncthreads();
#pragma unroll
    for (int kk = 0; kk < 16; ++kk)
      acc += xs[ty][kk] * wsm[tx][kk];
    __syncthreads();
  }
  out[(size_t)row * ODIM + colb + tx] = acc + bias[colb + tx];
}

extern "C" void kernel_launch(void* const* d_in, const int* in_sizes, int n_in,
                              void* d_out, int out_size, void* d_ws, size_t ws_size,
                              hipStream_t stream) {
  const float* x    = (const float*)d_in[0];
  const float* w    = (const float*)d_in[1];
  const float* bias = (const float*)d_in[2];
  float* out = (float*)d_out;

  const size_t needA = (size_t)NROWS * KDIM * sizeof(u16); // 16 MiB
  const size_t needB = (size_t)ODIM  * KDIM * sizeof(u16); //  8 MiB
  if (ws_size < needA + needB) {
    dim3 grid(ODIM / 16, NROWS / 16);
    fallback_gemm<<<grid, 256, 0, stream>>>(x, w, bias, out);
    return;
  }

  u16* xb = (u16*)d_ws;
  u16* wb = xb + (size_t)NROWS * KDIM;

  const int n4x = NROWS * KDIM / 4;  // 2M float4
  const int n4w = ODIM * KDIM / 4;   // 1M float4
  cvt_both_f32_to_bf16<<<2048, 256, 0, stream>>>(x, w, xb, wb, n4x, n4w);

  const int nblocks = (NROWS / BM) * (ODIM / BN);  // 16*16 = 256
  gemm_bt_bf16<<<nblocks, 512, 0, stream>>>(xb, wb, bias, out);
}